// Round 3
// baseline (118.330 us; speedup 1.0000x reference)
//
#include <hip/hip_runtime.h>
#include <stdint.h>

#define CCH 32
#define BATCH 512
#define NROW 1024   // 2*BATCH
#define DDIM 768
#define TILE 128
#define NPAIRS 36   // upper-tri tile pairs of 8x8
#define BK 32
#define NSTEP (DDIM / BK)   // 24
#define NKT 24              // K-tiles per channel

// Workspace bf16 tile layout: tile(c,kt,rt) = 8KB at ((c*24+kt)*8+rt)*4096 u16,
// within tile: [kslot 0..3][row 0..127][8 u16]  (kslot = 8 contiguous K elems = 16B)

typedef unsigned short u16;
typedef __attribute__((ext_vector_type(8))) short short8v;   // 8 bf16 (4 VGPRs)
typedef __attribute__((ext_vector_type(4))) float f32x4;     // MFMA acc

__device__ __forceinline__ u16 f2bf_rne(float x) {
    uint32_t u = __float_as_uint(x);
    u += 0x7FFFu + ((u >> 16) & 1u);
    return (u16)(u >> 16);
}
__device__ __forceinline__ float bf2f(u16 h) {
    return __uint_as_float(((uint32_t)h) << 16);
}

__device__ __forceinline__ void gload_lds16(const u16* g, u16* l) {
    __builtin_amdgcn_global_load_lds(
        (const __attribute__((address_space(1))) unsigned int*)(g),
        (__attribute__((address_space(3))) unsigned int*)(l),
        16, 0, 0);
}

__constant__ int PI_[NPAIRS] = {0,0,0,0,0,0,0,0, 1,1,1,1,1,1,1, 2,2,2,2,2,2,
                                3,3,3,3,3, 4,4,4,4, 5,5,5, 6,6, 7};
__constant__ int PJ_[NPAIRS] = {0,1,2,3,4,5,6,7, 1,2,3,4,5,6,7, 2,3,4,5,6,7,
                                3,4,5,6,7, 4,5,6,7, 5,6,7, 6,7, 7};

// ---------------- prep: fp32 -> bf16 K-major tiles + row norms (from bf16) -----------
__global__ __launch_bounds__(256) void k_prep(const float* __restrict__ src,
                                              const float* __restrict__ tgt,
                                              u16* __restrict__ bfbuf,
                                              float* __restrict__ sq) {
    int wid = threadIdx.x >> 6, lane = threadIdx.x & 63;
    int row = blockIdx.x * 4 + wid;      // [0, 32768): c*1024 + i
    int c = row >> 10, i = row & 1023;
    const float* rowp = (i < BATCH) ? (src + ((size_t)i * CCH + c) * DDIM)
                                    : (tgt + ((size_t)(i - BATCH) * CCH + c) * DDIM);
    // per-row base inside tile structure: + kt*32768 + ks*1024 + e
    u16* ob = bfbuf + ((size_t)c * 192 + (size_t)(i >> 7)) * 4096 + (size_t)(i & 127) * 8;
    float ss = 0.f;
#pragma unroll
    for (int j = 0; j < 3; ++j) {
        int d0 = (lane + j * 64) * 4;
        float4 v = *(reinterpret_cast<const float4*>(rowp) + lane + j * 64);
        u16 h0 = f2bf_rne(v.x), h1 = f2bf_rne(v.y), h2 = f2bf_rne(v.z), h3 = f2bf_rne(v.w);
        float f0 = bf2f(h0), f1 = bf2f(h1), f2 = bf2f(h2), f3 = bf2f(h3);
        ss += f0 * f0 + f1 * f1 + f2 * f2 + f3 * f3;
        ushort4 hv; hv.x = h0; hv.y = h1; hv.z = h2; hv.w = h3;
        int kt = d0 >> 5, ks = (d0 >> 3) & 3, e = d0 & 7;
        *reinterpret_cast<ushort4*>(ob + (size_t)kt * 32768 + ks * 1024 + e) = hv;
    }
#pragma unroll
    for (int off = 32; off > 0; off >>= 1) ss += __shfl_down(ss, off);
    if (lane == 0) sq[row] = ss;
}

// ---------------- fused colsum + bandwidth: one block per channel --------------------
// sum(d2) = 2n*sum(sq) - 2*||colsum||^2 ; bwc = -log2(e)/(16*bw)
__global__ __launch_bounds__(768) void k_csbw(const u16* __restrict__ bfbuf,
                                              const float* __restrict__ sq,
                                              float* __restrict__ bwc) {
    int c = blockIdx.x, t = threadIdx.x;
    int g = t / 96, s = t - g * 96;          // g: row-tile 0..7, s: 16B-slot 0..95
    int kt = s >> 2, ks = s & 3;
    const u16* base = bfbuf + ((size_t)c * 192 + (size_t)kt * 8 + g) * 4096 + ks * 1024;
    float a[8];
#pragma unroll
    for (int e = 0; e < 8; ++e) a[e] = 0.f;
#pragma unroll 2
    for (int rr = 0; rr < 128; ++rr) {
        short8v v = *reinterpret_cast<const short8v*>(base + (size_t)rr * 8);
#pragma unroll
        for (int e = 0; e < 8; ++e) a[e] += bf2f((u16)v[e]);
    }
    __shared__ float csl[8 * 768];           // 24 KB
#pragma unroll
    for (int e = 0; e < 8; ++e) csl[g * 768 + s * 8 + e] = a[e];
    __syncthreads();
    // per-column combine: column d == t (since (d>>3)*8 + (d&7) == d)
    float cs = 0.f;
#pragma unroll
    for (int g2 = 0; g2 < 8; ++g2) cs += csl[g2 * 768 + t];
    float v = -2.f * cs * cs;
    float sv = sq[(size_t)c * NROW + t];
    if (t < 256) sv += sq[(size_t)c * NROW + 768 + t];
    v += 2.f * (float)NROW * sv;
#pragma unroll
    for (int off = 32; off > 0; off >>= 1) v += __shfl_down(v, off);
    __syncthreads();                         // all csl reads done before reuse
    int wid = t >> 6, lane = t & 63;
    if (lane == 0) csl[wid] = v;
    __syncthreads();
    if (t == 0) {
        double sumd2 = 0.0;
        for (int w = 0; w < 12; ++w) sumd2 += (double)csl[w];
        double bw = sumd2 / ((double)NROW * (double)NROW - (double)NROW) / 4.0; // /2^(5//2)
        bwc[c] = (float)(-1.4426950408889634 / (16.0 * bw));  // exp2 scale, largest bw
    }
}

// ---------------- main: 3-buffer, 1-barrier/step pipelined GEMM + RBF epilogue -------
__global__ __launch_bounds__(512, 6) void k_mmd(const u16* __restrict__ bfbuf,
                                                const float* __restrict__ sq,
                                                const float* __restrict__ bwc,
                                                float* __restrict__ partial) {
    // bijective XCD swizzle: 1152 = 8 * 144 (4 channels contiguous per XCD)
    int orig = blockIdx.x;
    int blk = (orig & 7) * 144 + (orig >> 3);
    int c = blk / NPAIRS, p = blk - c * NPAIRS;
    int ti = PI_[p], tj = PJ_[p];
    const u16* At = bfbuf + ((size_t)c * 192 + ti) * 4096;   // + kt*32768
    const u16* Bt = bfbuf + ((size_t)c * 192 + tj) * 4096;

    __shared__ __align__(16) u16 lds[3][2][4096];            // 3 buf x (A,B) x 8KB = 48KB

    int t = threadIdx.x;
    int wid = t >> 6, lane = t & 63;
    int lr = lane & 15, kg = lane >> 4;
    int wrow = wid >> 2, wcol = wid & 3;     // 2x4 wave grid; wave owns 64x32

    auto STAGE = [&](int buf, int kt) {
        // LDS image == exact 8KB tile copy; dest = wave-uniform base + lane*16B
        gload_lds16(At + (size_t)kt * 32768 + (size_t)t * 8, &lds[buf][0][wid * 512]);
        gload_lds16(Bt + (size_t)kt * 32768 + (size_t)t * 8, &lds[buf][1][wid * 512]);
    };

    f32x4 acc[4][2];
#pragma unroll
    for (int m = 0; m < 4; ++m)
#pragma unroll
        for (int n = 0; n < 2; ++n) acc[m][n] = f32x4{0.f, 0.f, 0.f, 0.f};

    STAGE(0, 0);
    STAGE(1, 1);                              // 4 loads in flight

    for (int s = 0; s < NSTEP; ++s) {
        // outstanding here: stage(s)=2 + stage(s+1)=2 -> wait oldest 2 (= cur tile)
        if (s < NSTEP - 1) asm volatile("s_waitcnt vmcnt(2)" ::: "memory");
        else               asm volatile("s_waitcnt vmcnt(0)" ::: "memory");
        __builtin_amdgcn_s_barrier();         // all waves: cur tile resident in LDS
        asm volatile("" ::: "memory");
        if (s + 2 < NSTEP) STAGE((s + 2) % 3, s + 2);   // write-safe: readers passed bar(s)

        int cur = s % 3;
        const u16* LA = &lds[cur][0][0];
        const u16* LB = &lds[cur][1][0];
        short8v af[4], bf[2];
#pragma unroll
        for (int m = 0; m < 4; ++m)
            af[m] = *reinterpret_cast<const short8v*>(&LA[kg * 1024 + (wrow * 64 + m * 16 + lr) * 8]);
#pragma unroll
        for (int n = 0; n < 2; ++n)
            bf[n] = *reinterpret_cast<const short8v*>(&LB[kg * 1024 + (wcol * 32 + n * 16 + lr) * 8]);
#pragma unroll
        for (int m = 0; m < 4; ++m)
#pragma unroll
            for (int n = 0; n < 2; ++n)
                acc[m][n] = __builtin_amdgcn_mfma_f32_16x16x32_bf16(af[m], bf[n], acc[m][n], 0, 0, 0);
        // no trailing barrier: 3-buffer rotation makes one barrier/step sufficient
    }

    // epilogue: d2 -> sum_k exp(-d2/bw_k) via t + t^2 + t^4 + t^8 + t^16
    float ci = bwc[c];                        // -log2(e)/(16*bw)
    const float* sqc = sq + (size_t)c * NROW;
    float sqi[4][4], sqj[2];
#pragma unroll
    for (int m = 0; m < 4; ++m) {
        float4 s4 = *reinterpret_cast<const float4*>(&sqc[ti * TILE + wrow * 64 + m * 16 + kg * 4]);
        sqi[m][0] = s4.x; sqi[m][1] = s4.y; sqi[m][2] = s4.z; sqi[m][3] = s4.w;
    }
#pragma unroll
    for (int n = 0; n < 2; ++n)
        sqj[n] = sqc[tj * TILE + wcol * 32 + n * 16 + lr];

    float psum = 0.f;
#pragma unroll
    for (int m = 0; m < 4; ++m)
#pragma unroll
        for (int n = 0; n < 2; ++n) {
#pragma unroll
            for (int r = 0; r < 4; ++r) {
                // C/D layout (m89-verified): col = lane&15, row = (lane>>4)*4 + r
                float d2 = sqi[m][r] + sqj[n] - 2.0f * acc[m][n][r];
                float t1 = __builtin_amdgcn_exp2f(d2 * ci);
                float t2 = t1 * t1, t4 = t2 * t2, t8 = t4 * t4, t16 = t8 * t8;
                psum += ((t1 + t2) + (t4 + t8)) + t16;
            }
        }

#pragma unroll
    for (int off = 32; off > 0; off >>= 1) psum += __shfl_down(psum, off);
    float* red = reinterpret_cast<float*>(&lds[0][0][0]);
    __syncthreads();                          // loop reads done before LDS reuse
    if (lane == 0) red[wid] = psum;
    __syncthreads();
    if (t == 0) {
        float sblk = 0.f;
        for (int w = 0; w < 8; ++w) sblk += red[w];
        partial[blk] = sblk;
    }
}

// ---------------- final: deterministic combine of 32x36 tile sums --------------------
__global__ __launch_bounds__(64) void k_final(const float* __restrict__ partial,
                                              float* __restrict__ out) {
    int lane = threadIdx.x;
    double r = 0.0;
    if (lane < CCH) {
        const float* pp = partial + (size_t)lane * NPAIRS;
        double s = 0.0;
        for (int q = 0; q < NPAIRS; ++q) {
            int ti = PI_[q], tj = PJ_[q];
            double w = (ti == tj) ? 1.0 : 2.0;               // off-diag pair counted twice
            double sgn = ((ti < 4) == (tj < 4)) ? 1.0 : -1.0; // XX/YY : +, cross : -
            s += sgn * w * (double)pp[q];
        }
        r = s / ((double)BATCH * (double)BATCH);
    }
    for (int off = 16; off > 0; off >>= 1) r += __shfl_down(r, off);
    if (lane == 0) out[0] = (float)(r / (double)CCH);
}

extern "C" void kernel_launch(void* const* d_in, const int* in_sizes, int n_in,
                              void* d_out, int out_size, void* d_ws, size_t ws_size,
                              hipStream_t stream) {
    const float* src = (const float*)d_in[0];
    const float* tgt = (const float*)d_in[1];
    float* out = (float*)d_out;
    char* ws = (char*)d_ws;

    const size_t OFF_BF   = 0;                                       // 50,331,648 B
    const size_t OFF_SQ   = (size_t)CCH * NROW * DDIM * 2;           // +131,072 B
    const size_t OFF_BWC  = OFF_SQ + (size_t)CCH * NROW * 4;         // +128 B
    const size_t OFF_PART = OFF_BWC + (size_t)CCH * 4;               // +4,608 B

    u16*   bfbuf   = (u16*)(ws + OFF_BF);
    float* sq      = (float*)(ws + OFF_SQ);
    float* bwc     = (float*)(ws + OFF_BWC);
    float* partial = (float*)(ws + OFF_PART);

    k_prep<<<CCH * NROW / 4, 256, 0, stream>>>(src, tgt, bfbuf, sq);
    k_csbw<<<CCH, 768, 0, stream>>>(bfbuf, sq, bwc);
    k_mmd<<<CCH * NPAIRS, 512, 0, stream>>>(bfbuf, sq, bwc, partial);
    k_final<<<1, 64, 0, stream>>>(partial, out);
}

// Round 4
// 91.086 us; speedup vs baseline: 1.2991x; 1.2991x over previous
//
#include <hip/hip_runtime.h>
#include <stdint.h>

#define CCH 32
#define BATCH 512
#define NROW 1024   // 2*BATCH
#define DDIM 768
#define TILE 128
#define NPAIRS 36   // upper-tri tile pairs of 8x8
#define BK 32
#define NSTEP (DDIM / BK)   // 24

typedef unsigned short u16;
typedef __attribute__((ext_vector_type(8))) short short8v;   // 8 bf16 (4 VGPRs)
typedef __attribute__((ext_vector_type(4))) float f32x4;     // MFMA acc

__device__ __forceinline__ u16 f2bf_rne(float x) {
    uint32_t u = __float_as_uint(x);
    u += 0x7FFFu + ((u >> 16) & 1u);
    return (u16)(u >> 16);
}
__device__ __forceinline__ float bf2f(u16 h) {
    return __uint_as_float(((uint32_t)h) << 16);
}

__device__ __forceinline__ void gload_lds16(const u16* g, u16* l) {
    // async global->LDS, 16B per lane; LDS dest = wave-uniform base + lane*16
    __builtin_amdgcn_global_load_lds(
        (const __attribute__((address_space(1))) unsigned int*)(g),
        (__attribute__((address_space(3))) unsigned int*)(l),
        16, 0, 0);
}

__constant__ int PI_[NPAIRS] = {0,0,0,0,0,0,0,0, 1,1,1,1,1,1,1, 2,2,2,2,2,2,
                                3,3,3,3,3, 4,4,4,4, 5,5,5, 6,6, 7};
__constant__ int PJ_[NPAIRS] = {0,1,2,3,4,5,6,7, 1,2,3,4,5,6,7, 2,3,4,5,6,7,
                                3,4,5,6,7, 4,5,6,7, 5,6,7, 6,7, 7};

// ---------------- prep (R2, proven): fp32 -> bf16 row-major + row norms --------------
__global__ __launch_bounds__(256) void k_prep(const float* __restrict__ src,
                                              const float* __restrict__ tgt,
                                              u16* __restrict__ bfbuf,
                                              float* __restrict__ sq) {
    int wid = threadIdx.x >> 6, lane = threadIdx.x & 63;
    int row = blockIdx.x * 4 + wid;      // [0, 32768): c*1024 + i
    int c = row >> 10, i = row & 1023;
    const float* rowp = (i < BATCH) ? (src + ((size_t)i * CCH + c) * DDIM)
                                    : (tgt + ((size_t)(i - BATCH) * CCH + c) * DDIM);
    u16* orow = bfbuf + (size_t)row * DDIM;
    float ss = 0.f;
#pragma unroll
    for (int j = 0; j < 3; ++j) {
        float4 v = *(reinterpret_cast<const float4*>(rowp) + lane + j * 64);
        u16 h0 = f2bf_rne(v.x), h1 = f2bf_rne(v.y), h2 = f2bf_rne(v.z), h3 = f2bf_rne(v.w);
        float f0 = bf2f(h0), f1 = bf2f(h1), f2 = bf2f(h2), f3 = bf2f(h3);
        ss += f0 * f0 + f1 * f1 + f2 * f2 + f3 * f3;
        ushort4 hv; hv.x = h0; hv.y = h1; hv.z = h2; hv.w = h3;
        *reinterpret_cast<ushort4*>(orow + (size_t)(lane + j * 64) * 4) = hv;
    }
#pragma unroll
    for (int off = 32; off > 0; off >>= 1) ss += __shfl_down(ss, off);
    if (lane == 0) sq[row] = ss;
}

// ---------------- partial column sums over 128-row chunks (R2, proven) ---------------
__global__ __launch_bounds__(256) void k_colsum(const u16* __restrict__ bfbuf,
                                                float* __restrict__ colpart) {
    int c = blockIdx.x >> 3, ic = blockIdx.x & 7;
    const u16* base = bfbuf + ((size_t)c * NROW + (size_t)ic * 128) * DDIM;
#pragma unroll
    for (int j = 0; j < 3; ++j) {
        int d = threadIdx.x + j * 256;
        float s0 = 0.f, s1 = 0.f;
        for (int r = 0; r < 128; r += 2) {
            s0 += bf2f(base[(size_t)r * DDIM + d]);
            s1 += bf2f(base[(size_t)(r + 1) * DDIM + d]);
        }
        colpart[((size_t)c * 8 + ic) * DDIM + d] = s0 + s1;
    }
}

// ---------------- bandwidth: sum(d2) = 2n*sum(sq) - 2*||colsum||^2 -------------------
__global__ __launch_bounds__(256) void k_bw(const float* __restrict__ sq,
                                            const float* __restrict__ colpart,
                                            float* __restrict__ bwc) {
    int c = blockIdx.x, t = threadIdx.x;
    const float* sqc = sq + (size_t)c * NROW;
    float s = sqc[t] + sqc[t + 256] + sqc[t + 512] + sqc[t + 768];
    float s2 = 0.f;
#pragma unroll
    for (int j = 0; j < 3; ++j) {
        int d = t + j * 256;
        float cs = 0.f;
#pragma unroll
        for (int ic = 0; ic < 8; ++ic) cs += colpart[((size_t)c * 8 + ic) * DDIM + d];
        s2 += cs * cs;
    }
    __shared__ float redA[256], redB[256];
    redA[t] = s; redB[t] = s2;
    __syncthreads();
    for (int k = 128; k > 0; k >>= 1) {
        if (t < k) { redA[t] += redA[t + k]; redB[t] += redB[t + k]; }
        __syncthreads();
    }
    if (t == 0) {
        double sumd2 = 2.0 * (double)NROW * (double)redA[0] - 2.0 * (double)redB[0];
        double bw = sumd2 / ((double)NROW * (double)NROW - (double)NROW) / 4.0; // /2^(5//2)
        bwc[c] = (float)(-1.4426950408889634 / (16.0 * bw));  // exp2 scale, largest bw
    }
}

// ---------------- main: 3-buffer 1-barrier pipeline, 4 waves x 64x64 tile ------------
__global__ __launch_bounds__(256, 3) void k_mmd(const u16* __restrict__ bfbuf,
                                                const float* __restrict__ sq,
                                                const float* __restrict__ bwc,
                                                float* __restrict__ partial) {
    // bijective XCD swizzle: 1152 = 8 * 144 (4 channels contiguous per XCD)
    int orig = blockIdx.x;
    int blk = (orig & 7) * 144 + (orig >> 3);
    int c = blk / NPAIRS, p = blk - c * NPAIRS;
    int ti = PI_[p], tj = PJ_[p];
    const u16* Ab = bfbuf + ((size_t)c * NROW + (size_t)ti * TILE) * DDIM;
    const u16* Bb = bfbuf + ((size_t)c * NROW + (size_t)tj * TILE) * DDIM;

    __shared__ __align__(16) u16 lA[3][TILE * BK];   // 3 x 8 KB
    __shared__ __align__(16) u16 lB[3][TILE * BK];   // 3 x 8 KB  (48 KB total)

    int t = threadIdx.x;
    int wid = t >> 6, lane = t & 63;
    int lr = lane & 15, kg = lane >> 4;
    int wr = wid >> 1, wc = wid & 1;              // 2x2 wave grid; wave owns 64x64

    // stage one 128x32 A-tile + B-tile (R2-proven pattern: XOR-swizzled source chunk,
    // linear LDS dest = wave-uniform base + lane*16B)
    auto STAGE = [&](int buf, int k0) {
#pragma unroll
        for (int iss = 0; iss < 2; ++iss) {
            int g = t + iss * 256;                // granule: row = g>>2, slot = g&3
            int row = g >> 2;
            int kc = ((g & 3) ^ ((row >> 1) & 3)) * 8;   // inverse-swizzled source chunk
            const u16* ga = Ab + (size_t)row * DDIM + k0 + kc;
            const u16* gb = Bb + (size_t)row * DDIM + k0 + kc;
            u16* la = &lA[buf][(size_t)(wid * 64 + iss * 256) * 8];
            u16* lb = &lB[buf][(size_t)(wid * 64 + iss * 256) * 8];
            gload_lds16(ga, la);
            gload_lds16(gb, lb);
        }
    };

    f32x4 acc[4][4];
#pragma unroll
    for (int m = 0; m < 4; ++m)
#pragma unroll
        for (int n = 0; n < 4; ++n) acc[m][n] = f32x4{0.f, 0.f, 0.f, 0.f};

    // swizzled read slot (R2-proven, 0 conflicts): depends only on lr
    int ks = (kg ^ ((lr >> 1) & 3)) * 8;

    STAGE(0, 0);
    STAGE(1, BK);                                 // 8 loads in flight

    for (int s = 0; s < NSTEP; ++s) {
        // outstanding: stage(s)=4 + stage(s+1)=4 -> wait oldest 4 (= cur tile)
        if (s < NSTEP - 1) asm volatile("s_waitcnt vmcnt(4)" ::: "memory");
        else               asm volatile("s_waitcnt vmcnt(0)" ::: "memory");
        __builtin_amdgcn_s_barrier();             // all waves: cur tile resident
        asm volatile("" ::: "memory");
        if (s + 2 < NSTEP) STAGE((s + 2) % 3, (s + 2) * BK);  // 2-ahead prefetch

        int cur = s % 3;
        short8v af[4], bf[4];
#pragma unroll
        for (int m = 0; m < 4; ++m)
            af[m] = *reinterpret_cast<const short8v*>(&lA[cur][(wr * 64 + m * 16 + lr) * BK + ks]);
#pragma unroll
        for (int n = 0; n < 4; ++n)
            bf[n] = *reinterpret_cast<const short8v*>(&lB[cur][(wc * 64 + n * 16 + lr) * BK + ks]);
#pragma unroll
        for (int m = 0; m < 4; ++m)
#pragma unroll
            for (int n = 0; n < 4; ++n)
                acc[m][n] = __builtin_amdgcn_mfma_f32_16x16x32_bf16(af[m], bf[n], acc[m][n], 0, 0, 0);
        // no trailing barrier: 3-buffer rotation, writer targets buf two steps ahead
    }

    // epilogue: d2 -> sum_k exp(-d2/bw_k) via t + t^2 + t^4 + t^8 + t^16
    float ci = bwc[c];                            // -log2(e)/(16*bw)
    const float* sqc = sq + (size_t)c * NROW;
    float sqi[4][4], sqj[4];
#pragma unroll
    for (int m = 0; m < 4; ++m) {
        float4 s4 = *reinterpret_cast<const float4*>(&sqc[ti * TILE + wr * 64 + m * 16 + kg * 4]);
        sqi[m][0] = s4.x; sqi[m][1] = s4.y; sqi[m][2] = s4.z; sqi[m][3] = s4.w;
    }
#pragma unroll
    for (int n = 0; n < 4; ++n)
        sqj[n] = sqc[tj * TILE + wc * 64 + n * 16 + lr];

    float psum = 0.f;
#pragma unroll
    for (int m = 0; m < 4; ++m)
#pragma unroll
        for (int n = 0; n < 4; ++n) {
#pragma unroll
            for (int r = 0; r < 4; ++r) {
                // C/D layout (m89-verified): col = lane&15, row = (lane>>4)*4 + r
                float d2 = sqi[m][r] + sqj[n] - 2.0f * acc[m][n][r];
                float t1 = __builtin_amdgcn_exp2f(d2 * ci);
                float t2 = t1 * t1, t4 = t2 * t2, t8 = t4 * t4, t16 = t8 * t8;
                psum += ((t1 + t2) + (t4 + t8)) + t16;
            }
        }

#pragma unroll
    for (int off = 32; off > 0; off >>= 1) psum += __shfl_down(psum, off);
    float* red = reinterpret_cast<float*>(&lA[0][0]);
    __syncthreads();                              // all LDS reads done before reuse
    if (lane == 0) red[wid] = psum;
    __syncthreads();
    if (t == 0) {
        float sblk = 0.f;
        for (int w = 0; w < 4; ++w) sblk += red[w];
        partial[blk] = sblk;
    }
}

// ---------------- final: deterministic combine of 32x36 tile sums --------------------
__global__ __launch_bounds__(64) void k_final(const float* __restrict__ partial,
                                              float* __restrict__ out) {
    int lane = threadIdx.x;
    double r = 0.0;
    if (lane < CCH) {
        const float* pp = partial + (size_t)lane * NPAIRS;
        double s = 0.0;
        for (int q = 0; q < NPAIRS; ++q) {
            int ti = PI_[q], tj = PJ_[q];
            double w = (ti == tj) ? 1.0 : 2.0;               // off-diag pair counted twice
            double sgn = ((ti < 4) == (tj < 4)) ? 1.0 : -1.0; // XX/YY : +, cross : -
            s += sgn * w * (double)pp[q];
        }
        r = s / ((double)BATCH * (double)BATCH);
    }
    for (int off = 16; off > 0; off >>= 1) r += __shfl_down(r, off);
    if (lane == 0) out[0] = (float)(r / (double)CCH);
}

extern "C" void kernel_launch(void* const* d_in, const int* in_sizes, int n_in,
                              void* d_out, int out_size, void* d_ws, size_t ws_size,
                              hipStream_t stream) {
    const float* src = (const float*)d_in[0];
    const float* tgt = (const float*)d_in[1];
    float* out = (float*)d_out;
    char* ws = (char*)d_ws;

    const size_t OFF_BF   = 0;                                       // 50,331,648 B
    const size_t OFF_SQ   = (size_t)CCH * NROW * DDIM * 2;           // +131,072 B
    const size_t OFF_CP   = OFF_SQ + (size_t)CCH * NROW * 4;         // +786,432 B
    const size_t OFF_BWC  = OFF_CP + (size_t)CCH * 8 * DDIM * 4;     // +128 B
    const size_t OFF_PART = OFF_BWC + (size_t)CCH * 4;               // +4,608 B

    u16*   bfbuf   = (u16*)(ws + OFF_BF);
    float* sq      = (float*)(ws + OFF_SQ);
    float* colpart = (float*)(ws + OFF_CP);
    float* bwc     = (float*)(ws + OFF_BWC);
    float* partial = (float*)(ws + OFF_PART);

    k_prep<<<CCH * NROW / 4, 256, 0, stream>>>(src, tgt, bfbuf, sq);
    k_colsum<<<CCH * 8, 256, 0, stream>>>(bfbuf, colpart);
    k_bw<<<CCH, 256, 0, stream>>>(sq, colpart, bwc);
    k_mmd<<<CCH * NPAIRS, 256, 0, stream>>>(bfbuf, sq, bwc, partial);
    k_final<<<1, 64, 0, stream>>>(partial, out);
}

// Round 5
// 85.427 us; speedup vs baseline: 1.3852x; 1.0662x over previous
//
#include <hip/hip_runtime.h>
#include <stdint.h>

#define CCH 32
#define BATCH 512
#define NROW 1024   // 2*BATCH
#define DDIM 768
#define TILE 128
#define NPAIRS 36   // upper-tri tile pairs of 8x8
#define BK 32
#define NSTEP (DDIM / BK)   // 24

typedef unsigned short u16;
typedef __attribute__((ext_vector_type(8))) short short8v;   // 8 bf16 (4 VGPRs)
typedef __attribute__((ext_vector_type(4))) float f32x4;     // MFMA acc

__device__ __forceinline__ u16 f2bf_rne(float x) {
    uint32_t u = __float_as_uint(x);
    u += 0x7FFFu + ((u >> 16) & 1u);
    return (u16)(u >> 16);
}
__device__ __forceinline__ float bf2f(u16 h) {
    return __uint_as_float(((uint32_t)h) << 16);
}

__device__ __forceinline__ void gload_lds16(const u16* g, u16* l) {
    // async global->LDS, 16B per lane; LDS dest = wave-uniform base + lane*16
    __builtin_amdgcn_global_load_lds(
        (const __attribute__((address_space(1))) unsigned int*)(g),
        (__attribute__((address_space(3))) unsigned int*)(l),
        16, 0, 0);
}

__constant__ int PI_[NPAIRS] = {0,0,0,0,0,0,0,0, 1,1,1,1,1,1,1, 2,2,2,2,2,2,
                                3,3,3,3,3, 4,4,4,4, 5,5,5, 6,6, 7};
__constant__ int PJ_[NPAIRS] = {0,1,2,3,4,5,6,7, 1,2,3,4,5,6,7, 2,3,4,5,6,7,
                                3,4,5,6,7, 4,5,6,7, 5,6,7, 6,7, 7};

// ---------------- prep (R2, proven): fp32 -> bf16 row-major + row norms --------------
__global__ __launch_bounds__(256) void k_prep(const float* __restrict__ src,
                                              const float* __restrict__ tgt,
                                              u16* __restrict__ bfbuf,
                                              float* __restrict__ sq) {
    int wid = threadIdx.x >> 6, lane = threadIdx.x & 63;
    int row = blockIdx.x * 4 + wid;      // [0, 32768): c*1024 + i
    int c = row >> 10, i = row & 1023;
    const float* rowp = (i < BATCH) ? (src + ((size_t)i * CCH + c) * DDIM)
                                    : (tgt + ((size_t)(i - BATCH) * CCH + c) * DDIM);
    u16* orow = bfbuf + (size_t)row * DDIM;
    float ss = 0.f;
#pragma unroll
    for (int j = 0; j < 3; ++j) {
        float4 v = *(reinterpret_cast<const float4*>(rowp) + lane + j * 64);
        u16 h0 = f2bf_rne(v.x), h1 = f2bf_rne(v.y), h2 = f2bf_rne(v.z), h3 = f2bf_rne(v.w);
        float f0 = bf2f(h0), f1 = bf2f(h1), f2 = bf2f(h2), f3 = bf2f(h3);
        ss += f0 * f0 + f1 * f1 + f2 * f2 + f3 * f3;
        ushort4 hv; hv.x = h0; hv.y = h1; hv.z = h2; hv.w = h3;
        *reinterpret_cast<ushort4*>(orow + (size_t)(lane + j * 64) * 4) = hv;
    }
#pragma unroll
    for (int off = 32; off > 0; off >>= 1) ss += __shfl_down(ss, off);
    if (lane == 0) sq[row] = ss;
}

// ---------------- partial column sums over 128-row chunks (R2, proven) ---------------
__global__ __launch_bounds__(256) void k_colsum(const u16* __restrict__ bfbuf,
                                                float* __restrict__ colpart) {
    int c = blockIdx.x >> 3, ic = blockIdx.x & 7;
    const u16* base = bfbuf + ((size_t)c * NROW + (size_t)ic * 128) * DDIM;
#pragma unroll
    for (int j = 0; j < 3; ++j) {
        int d = threadIdx.x + j * 256;
        float s0 = 0.f, s1 = 0.f;
        for (int r = 0; r < 128; r += 2) {
            s0 += bf2f(base[(size_t)r * DDIM + d]);
            s1 += bf2f(base[(size_t)(r + 1) * DDIM + d]);
        }
        colpart[((size_t)c * 8 + ic) * DDIM + d] = s0 + s1;
    }
}

// ---------------- bandwidth: sum(d2) = 2n*sum(sq) - 2*||colsum||^2 -------------------
__global__ __launch_bounds__(256) void k_bw(const float* __restrict__ sq,
                                            const float* __restrict__ colpart,
                                            float* __restrict__ bwc) {
    int c = blockIdx.x, t = threadIdx.x;
    const float* sqc = sq + (size_t)c * NROW;
    float s = sqc[t] + sqc[t + 256] + sqc[t + 512] + sqc[t + 768];
    float s2 = 0.f;
#pragma unroll
    for (int j = 0; j < 3; ++j) {
        int d = t + j * 256;
        float cs = 0.f;
#pragma unroll
        for (int ic = 0; ic < 8; ++ic) cs += colpart[((size_t)c * 8 + ic) * DDIM + d];
        s2 += cs * cs;
    }
    __shared__ float redA[256], redB[256];
    redA[t] = s; redB[t] = s2;
    __syncthreads();
    for (int k = 128; k > 0; k >>= 1) {
        if (t < k) { redA[t] += redA[t + k]; redB[t] += redB[t + k]; }
        __syncthreads();
    }
    if (t == 0) {
        double sumd2 = 2.0 * (double)NROW * (double)redA[0] - 2.0 * (double)redB[0];
        double bw = sumd2 / ((double)NROW * (double)NROW - (double)NROW) / 4.0; // /2^(5//2)
        bwc[c] = (float)(-1.4426950408889634 / (16.0 * bw));  // exp2 scale, largest bw
    }
}

// ---------------- main: 3-buffer 1-barrier pipeline, FULLY UNROLLED K-loop -----------
__global__ __launch_bounds__(256, 3) void k_mmd(const u16* __restrict__ bfbuf,
                                                const float* __restrict__ sq,
                                                const float* __restrict__ bwc,
                                                float* __restrict__ partial) {
    // bijective XCD swizzle: 1152 = 8 * 144 (4 channels contiguous per XCD)
    int orig = blockIdx.x;
    int blk = (orig & 7) * 144 + (orig >> 3);
    int c = blk / NPAIRS, p = blk - c * NPAIRS;
    int ti = PI_[p], tj = PJ_[p];
    const u16* Ab = bfbuf + ((size_t)c * NROW + (size_t)ti * TILE) * DDIM;
    const u16* Bb = bfbuf + ((size_t)c * NROW + (size_t)tj * TILE) * DDIM;

    __shared__ __align__(16) u16 lA[3][TILE * BK];   // 3 x 8 KB
    __shared__ __align__(16) u16 lB[3][TILE * BK];   // 3 x 8 KB  (48 KB total)

    int t = threadIdx.x;
    int wid = t >> 6, lane = t & 63;
    int lr = lane & 15, kg = lane >> 4;
    int wr = wid >> 1, wc = wid & 1;              // 2x2 wave grid; wave owns 64x64

    // Per-lane invariant pieces of the staging addresses (hoisted once):
    // granule g = t + iss*256: row = g>>2, swizzled chunk kc = ((g&3)^((row>>1)&3))*8
    int g0 = t, row0 = g0 >> 2, kc0 = ((g0 & 3) ^ ((row0 >> 1) & 3)) * 8;
    int g1 = t + 256, row1 = g1 >> 2, kc1 = ((g1 & 3) ^ ((row1 >> 1) & 3)) * 8;
    const u16* gA0 = Ab + (size_t)row0 * DDIM + kc0;
    const u16* gA1 = Ab + (size_t)row1 * DDIM + kc1;
    const u16* gB0 = Bb + (size_t)row0 * DDIM + kc0;
    const u16* gB1 = Bb + (size_t)row1 * DDIM + kc1;
    u16* lba0;  // wave-uniform LDS dest offsets (same for every buffer, + buf base)
    u16* lbb0;
    // dest granule base: (wid*64 + iss*256)*8 u16
    auto STAGE = [&](int buf, int k0) {
        gload_lds16(gA0 + k0, &lA[buf][(size_t)(wid * 64) * 8]);
        gload_lds16(gB0 + k0, &lB[buf][(size_t)(wid * 64) * 8]);
        gload_lds16(gA1 + k0, &lA[buf][(size_t)(wid * 64 + 256) * 8]);
        gload_lds16(gB1 + k0, &lB[buf][(size_t)(wid * 64 + 256) * 8]);
    };
    (void)lba0; (void)lbb0;

    f32x4 acc[4][4];
#pragma unroll
    for (int m = 0; m < 4; ++m)
#pragma unroll
        for (int n = 0; n < 4; ++n) acc[m][n] = f32x4{0.f, 0.f, 0.f, 0.f};

    // swizzled read slot (R2-proven, 0 conflicts): depends only on lr
    int ks = (kg ^ ((lr >> 1) & 3)) * 8;
    // per-lane LDS read byte offsets within a buffer (static across steps)
    int raddrA = (wr * 64 + lr) * BK + ks;        // + m*16*BK
    int raddrB = (wc * 64 + lr) * BK + ks;        // + n*16*BK

    STAGE(0, 0);
    STAGE(1, BK);                                 // 8 loads in flight

#pragma unroll
    for (int s = 0; s < NSTEP; ++s) {
        // outstanding: stage(s)=4 + stage(s+1)=4 -> wait oldest 4 (= cur tile)
        if (s < NSTEP - 1) asm volatile("s_waitcnt vmcnt(4)" ::: "memory");
        else               asm volatile("s_waitcnt vmcnt(0)" ::: "memory");
        asm volatile("s_barrier" ::: "memory");   // all waves: cur tile resident
        if (s + 2 < NSTEP) STAGE((s + 2) % 3, (s + 2) * BK);  // static buf after unroll

        const int cur = s % 3;                    // compile-time constant per copy
        short8v af[4], bf[4];
#pragma unroll
        for (int m = 0; m < 4; ++m)
            af[m] = *reinterpret_cast<const short8v*>(&lA[cur][raddrA + m * 16 * BK]);
#pragma unroll
        for (int n = 0; n < 4; ++n)
            bf[n] = *reinterpret_cast<const short8v*>(&lB[cur][raddrB + n * 16 * BK]);
#pragma unroll
        for (int m = 0; m < 4; ++m)
#pragma unroll
            for (int n = 0; n < 4; ++n)
                acc[m][n] = __builtin_amdgcn_mfma_f32_16x16x32_bf16(af[m], bf[n], acc[m][n], 0, 0, 0);
        // no trailing barrier: 3-buffer rotation, writer targets buf two steps ahead
    }

    // epilogue: d2 -> sum_k exp(-d2/bw_k) via t + t^2 + t^4 + t^8 + t^16
    float ci = bwc[c];                            // -log2(e)/(16*bw)
    const float* sqc = sq + (size_t)c * NROW;
    float sqi[4][4], sqj[4];
#pragma unroll
    for (int m = 0; m < 4; ++m) {
        float4 s4 = *reinterpret_cast<const float4*>(&sqc[ti * TILE + wr * 64 + m * 16 + kg * 4]);
        sqi[m][0] = s4.x; sqi[m][1] = s4.y; sqi[m][2] = s4.z; sqi[m][3] = s4.w;
    }
#pragma unroll
    for (int n = 0; n < 4; ++n)
        sqj[n] = sqc[tj * TILE + wc * 64 + n * 16 + lr];

    float psum = 0.f;
#pragma unroll
    for (int m = 0; m < 4; ++m)
#pragma unroll
        for (int n = 0; n < 4; ++n) {
#pragma unroll
            for (int r = 0; r < 4; ++r) {
                // C/D layout (m89-verified): col = lane&15, row = (lane>>4)*4 + r
                float d2 = sqi[m][r] + sqj[n] - 2.0f * acc[m][n][r];
                float t1 = __builtin_amdgcn_exp2f(d2 * ci);
                float t2 = t1 * t1, t4 = t2 * t2, t8 = t4 * t4, t16 = t8 * t8;
                psum += ((t1 + t2) + (t4 + t8)) + t16;
            }
        }

#pragma unroll
    for (int off = 32; off > 0; off >>= 1) psum += __shfl_down(psum, off);
    float* red = reinterpret_cast<float*>(&lA[0][0]);
    __syncthreads();                              // all LDS reads done before reuse
    if (lane == 0) red[wid] = psum;
    __syncthreads();
    if (t == 0) {
        float sblk = 0.f;
        for (int w = 0; w < 4; ++w) sblk += red[w];
        partial[blk] = sblk;
    }
}

// ---------------- final: deterministic combine of 32x36 tile sums --------------------
__global__ __launch_bounds__(64) void k_final(const float* __restrict__ partial,
                                              float* __restrict__ out) {
    int lane = threadIdx.x;
    double r = 0.0;
    if (lane < CCH) {
        const float* pp = partial + (size_t)lane * NPAIRS;
        double s = 0.0;
        for (int q = 0; q < NPAIRS; ++q) {
            int ti = PI_[q], tj = PJ_[q];
            double w = (ti == tj) ? 1.0 : 2.0;               // off-diag pair counted twice
            double sgn = ((ti < 4) == (tj < 4)) ? 1.0 : -1.0; // XX/YY : +, cross : -
            s += sgn * w * (double)pp[q];
        }
        r = s / ((double)BATCH * (double)BATCH);
    }
    for (int off = 16; off > 0; off >>= 1) r += __shfl_down(r, off);
    if (lane == 0) out[0] = (float)(r / (double)CCH);
}

extern "C" void kernel_launch(void* const* d_in, const int* in_sizes, int n_in,
                              void* d_out, int out_size, void* d_ws, size_t ws_size,
                              hipStream_t stream) {
    const float* src = (const float*)d_in[0];
    const float* tgt = (const float*)d_in[1];
    float* out = (float*)d_out;
    char* ws = (char*)d_ws;

    const size_t OFF_BF   = 0;                                       // 50,331,648 B
    const size_t OFF_SQ   = (size_t)CCH * NROW * DDIM * 2;           // +131,072 B
    const size_t OFF_CP   = OFF_SQ + (size_t)CCH * NROW * 4;         // +786,432 B
    const size_t OFF_BWC  = OFF_CP + (size_t)CCH * 8 * DDIM * 4;     // +128 B
    const size_t OFF_PART = OFF_BWC + (size_t)CCH * 4;               // +4,608 B

    u16*   bfbuf   = (u16*)(ws + OFF_BF);
    float* sq      = (float*)(ws + OFF_SQ);
    float* colpart = (float*)(ws + OFF_CP);
    float* bwc     = (float*)(ws + OFF_BWC);
    float* partial = (float*)(ws + OFF_PART);

    k_prep<<<CCH * NROW / 4, 256, 0, stream>>>(src, tgt, bfbuf, sq);
    k_colsum<<<CCH * 8, 256, 0, stream>>>(bfbuf, colpart);
    k_bw<<<CCH, 256, 0, stream>>>(sq, colpart, bwc);
    k_mmd<<<CCH * NPAIRS, 256, 0, stream>>>(bfbuf, sq, bwc, partial);
    k_final<<<1, 64, 0, stream>>>(partial, out);
}